// Round 1
// baseline (134.507 us; speedup 1.0000x reference)
//
#include <hip/hip_runtime.h>
#include <math.h>

#define B_MOL 64
#define A_MAX 48
#define NSPEC 4
#define NRS2 24
#define NRS3 20
#define NPAIRS 10
#define REP2 (NSPEC * NRS2)        // 96
#define REP3 (NPAIRS * NRS3 * 2)   // 400
#define REPTOT (REP2 + REP3)       // 496

#define RCUT_F 6.0f
#define ETA2_F 0.32f
#define ETA3_F 2.7f
#define PI_F 3.14159265358979323846f
#define W3_F 12.4225780586f        // sqrt(2.7/pi)*13.4
#define SQRT_2PI_F 2.5066282746310002f

__global__ __launch_bounds__(256) void fchl_kernel(
    const float* __restrict__ X, const int* __restrict__ Z,
    const int* __restrict__ atom_counts, float* __restrict__ out)
{
    const int bi = blockIdx.x;           // b*A_MAX + i
    const int b = bi / A_MAX;
    const int i = bi % A_MAX;
    const int tid = threadIdx.x;
    const int nthr = blockDim.x;

    __shared__ float sxs[A_MAX], sys[A_MAX], szs[A_MAX];
    __shared__ int   sZ[A_MAX];
    // candidate (per original j) stage
    __shared__ float cand_dx[A_MAX], cand_dy[A_MAX], cand_dz[A_MAX], cand_r[A_MAX];
    __shared__ int   cand_flag[A_MAX];
    // compacted neighbor list (order-preserving => local a<c <=> original j<k)
    __shared__ float nb_dx[A_MAX], nb_dy[A_MAX], nb_dz[A_MAX], nb_r[A_MAX];
    __shared__ float nb_fc[A_MAX], nb_mu[A_MAX], nb_i2s2[A_MAX], nb_pref[A_MAX];
    __shared__ int   nb_z[A_MAX];
    __shared__ int   nb_m;
    __shared__ float rep3s[REP3];

    const int cnt = atom_counts[b];

    if (tid < A_MAX) {
        sxs[tid] = X[(b * A_MAX + tid) * 3 + 0];
        sys[tid] = X[(b * A_MAX + tid) * 3 + 1];
        szs[tid] = X[(b * A_MAX + tid) * 3 + 2];
        sZ[tid]  = Z[b * A_MAX + tid];
    }
    for (int t = tid; t < REP3; t += nthr) rep3s[t] = 0.0f;
    __syncthreads();

    const float xi = sxs[i], yi = sys[i], zi = szs[i];
    const bool ivalid = (i < cnt);

    if (tid < A_MAX) {
        const int j = tid;
        float dx = xi - sxs[j], dy = yi - sys[j], dz = zi - szs[j];
        float r = sqrtf(dx * dx + dy * dy + dz * dz);
        cand_flag[j] = (ivalid && j < cnt && j != i && r < RCUT_F) ? 1 : 0;
        cand_dx[j] = dx; cand_dy[j] = dy; cand_dz[j] = dz; cand_r[j] = r;
    }
    __syncthreads();
    if (tid == 0) {
        int m = 0;
        for (int j = 0; j < A_MAX; ++j) {
            if (cand_flag[j]) {
                nb_dx[m] = cand_dx[j]; nb_dy[m] = cand_dy[j]; nb_dz[m] = cand_dz[j];
                nb_r[m]  = cand_r[j];  nb_z[m]  = sZ[j];
                ++m;
            }
        }
        nb_m = m;
    }
    __syncthreads();
    const int m = nb_m;

    // per-neighbor two-body precompute
    if (tid < m) {
        float r = nb_r[tid];
        float fc = 0.5f * (cosf(PI_F * r * (1.0f / RCUT_F)) + 1.0f);
        float lr = logf(r);
        float s2 = log1pf(ETA2_F / (r * r));
        nb_fc[tid]   = fc;
        nb_mu[tid]   = lr - 0.5f * s2;
        nb_i2s2[tid] = 1.0f / (2.0f * s2);
        nb_pref[tid] = fc * expf(-1.8f * lr) / (sqrtf(s2) * SQRT_2PI_F);
    }
    __syncthreads();

    float* orow = out + (size_t)bi * REPTOT;

    // ---- two-body: thread t owns output (s, n) = (t/24, t%24) ----
    if (tid < REP2) {
        const int s = tid / NRS2;
        const int n = tid % NRS2;
        const float Rn = 0.25f * (float)(n + 1);   // RS2[n]
        const float logRn = logf(Rn);
        float acc = 0.0f;
        for (int a = 0; a < m; ++a) {
            if (nb_z[a] == s) {
                float dmu = logRn - nb_mu[a];
                acc += nb_pref[a] * expf(-dmu * dmu * nb_i2s2[a]);
            }
        }
        orow[tid] = acc * (1.0f / Rn);
    }

    // ---- three-body: one triplet (a<c in neighbor list) per thread ----
    const int ntrip = m * (m - 1) / 2;
    for (int t = tid; t < ntrip; t += nthr) {
        // decode linear index -> (a, c), a < c
        int rem = t, a = 0, rl = m - 1;
        while (rem >= rl) { rem -= rl; --rl; ++a; }
        const int c = a + 1 + rem;

        const float rij = nb_r[a], rik = nb_r[c];
        const float djx = nb_dx[a], djy = nb_dy[a], djz = nb_dz[a];
        const float dkx = nb_dx[c], dky = nb_dy[c], dkz = nb_dz[c];

        float cosi = (djx * dkx + djy * dky + djz * dkz) / (rij * rik);
        cosi = fminf(1.0f, fmaxf(-1.0f, cosi));

        // r_jk: REFERENCE SEMANTICS: clamped to 1.0 if the (j,k) pair is not
        // itself within the cutoff (rs = where(within, r, 1.0)).
        const float ex = dkx - djx, ey = dky - djy, ez = dkz - djz;
        const float rjk = sqrtf(ex * ex + ey * ey + ez * ez);
        const float rjke = (rjk < RCUT_F) ? rjk : 1.0f;

        const float cosj = (rij * rij + rjke * rjke - rik * rik) / (2.0f * rij * rjke);
        const float cosk = (rik * rik + rjke * rjke - rij * rij) / (2.0f * rik * rjke);

        const float ksi = W3_F * (1.0f + 3.0f * cosi * cosj * cosk)
                        * expf(-0.57f * logf(rij * rik * rjke));
        const float w  = ksi * nb_fc[a] * nb_fc[c];
        const float wc = w * cosi;
        const float s1 = fmaxf(1.0f - cosi * cosi, 0.0f);
        const float ws = w * sqrtf(s1);
        const float d  = 0.5f * (rij + rik);

        const int zj = nb_z[a], zk = nb_z[c];
        const int pmn = min(zj, zk), pmx = max(zj, zk);
        const int p = (pmn * (2 * NSPEC - pmn - 1)) / 2 + pmx;

        float* dst = &rep3s[p * NRS3 * 2];
        #pragma unroll
        for (int l = 0; l < NRS3; ++l) {
            const float dd = d - 0.3f * (float)(l + 1);   // RS3[l]
            const float rad = expf(-ETA3_F * dd * dd);
            atomicAdd(&dst[l * 2 + 0], wc * rad);
            atomicAdd(&dst[l * 2 + 1], ws * rad);
        }
    }
    __syncthreads();

    for (int t = tid; t < REP3; t += nthr) orow[REP2 + t] = rep3s[t];
}

extern "C" void kernel_launch(void* const* d_in, const int* in_sizes, int n_in,
                              void* d_out, int out_size, void* d_ws, size_t ws_size,
                              hipStream_t stream) {
    const float* X           = (const float*)d_in[0];
    const int*   Z           = (const int*)d_in[1];
    // d_in[2] = atomIDs, d_in[3] = molIDs (unused by reference math)
    const int*   atom_counts = (const int*)d_in[4];
    float* out = (float*)d_out;

    fchl_kernel<<<B_MOL * A_MAX, 256, 0, stream>>>(X, Z, atom_counts, out);
}

// Round 2
// 74.407 us; speedup vs baseline: 1.8077x; 1.8077x over previous
//
#include <hip/hip_runtime.h>
#include <math.h>

#define B_MOL 64
#define A_MAX 48
#define NSPEC 4
#define NRS2 24
#define NRS3 20
#define NPAIRS 10
#define REP2 (NSPEC * NRS2)        // 96
#define REP3 (NPAIRS * NRS3 * 2)   // 400
#define REPTOT (REP2 + REP3)       // 496
#define TRIP_CAP (A_MAX * (A_MAX - 1) / 2 + 1)  // 1129 (>= 47*46/2=1081)

#define RCUT_F 6.0f
#define ETA2_F 0.32f
#define ETA3_F 2.7f
#define PI_F 3.14159265358979323846f
#define W3_F 12.4225780586f        // sqrt(2.7/pi)*13.4
#define SQRT_2PI_F 2.5066282746310002f

__global__ __launch_bounds__(256) void fchl_kernel(
    const float* __restrict__ X, const int* __restrict__ Z,
    const int* __restrict__ atom_counts, float* __restrict__ out)
{
    const int bi = blockIdx.x;           // b*A_MAX + i
    const int b = bi / A_MAX;
    const int i = bi % A_MAX;
    const int tid = threadIdx.x;

    __shared__ float sx[A_MAX], sy[A_MAX], sz[A_MAX];
    __shared__ int   sZa[A_MAX];
    // compacted neighbor list (ballot compaction is order-preserving =>
    // local a<c <=> original j<k)
    __shared__ float nb_dx[A_MAX], nb_dy[A_MAX], nb_dz[A_MAX], nb_r[A_MAX];
    __shared__ float nb_fc[A_MAX], nb_mu[A_MAX], nb_i2s2[A_MAX], nb_pref[A_MAX];
    __shared__ int   nb_z[A_MAX];
    __shared__ int   nb_m;
    // triplet buckets by pair-species index p
    __shared__ int   bcnt[NPAIRS], bstart[NPAIRS], bcur[NPAIRS];
    __shared__ float trip_wc[TRIP_CAP], trip_ws[TRIP_CAP], trip_d[TRIP_CAP];

    const int cnt = atom_counts[b];

    if (tid < A_MAX) {
        sx[tid]  = X[(b * A_MAX + tid) * 3 + 0];
        sy[tid]  = X[(b * A_MAX + tid) * 3 + 1];
        sz[tid]  = X[(b * A_MAX + tid) * 3 + 2];
        sZa[tid] = Z[b * A_MAX + tid];
    }
    if (tid < NPAIRS) bcnt[tid] = 0;
    __syncthreads();

    const float xi = sx[i], yi = sy[i], zi = sz[i];
    const bool ivalid = (i < cnt);

    // ---- Phase A: ballot-compacted neighbor list + per-neighbor precompute ----
    if (tid < 64) {
        const int j = tid;
        bool flag = false;
        float dx = 0.f, dy = 0.f, dz = 0.f, r = 1.f;
        if (j < A_MAX) {
            dx = xi - sx[j]; dy = yi - sy[j]; dz = zi - sz[j];
            r = sqrtf(dx * dx + dy * dy + dz * dz);
            flag = ivalid && (j < cnt) && (j != i) && (r < RCUT_F);
        }
        const unsigned long long mask = __ballot(flag ? 1 : 0);
        if (flag) {
            const int pos = __popcll(mask & ((1ull << tid) - 1ull));
            nb_dx[pos] = dx; nb_dy[pos] = dy; nb_dz[pos] = dz;
            nb_r[pos]  = r;  nb_z[pos]  = sZa[j];
            const float fc = 0.5f * (__cosf(PI_F * r * (1.0f / RCUT_F)) + 1.0f);
            const float lr = __logf(r);
            const float s2 = log1pf(ETA2_F / (r * r));
            nb_fc[pos]   = fc;
            nb_mu[pos]   = lr - 0.5f * s2;
            nb_i2s2[pos] = 1.0f / (2.0f * s2);
            nb_pref[pos] = fc * __expf(-1.8f * lr) / (sqrtf(s2) * SQRT_2PI_F);
        }
        if (tid == 0) nb_m = (int)__popcll(mask);
    }
    __syncthreads();
    const int m = nb_m;
    const int ntrip = m * (m - 1) / 2;

    float* orow = out + (size_t)bi * REPTOT;

    // ---- two-body: thread t owns output (s, n) = (t/24, t%24) ----
    if (tid < REP2) {
        const int s = tid / NRS2;
        const int n = tid % NRS2;
        const float Rn = 0.25f * (float)(n + 1);   // RS2[n]
        const float logRn = __logf(Rn);
        float acc = 0.0f;
        for (int a = 0; a < m; ++a) {
            if (nb_z[a] == s) {
                const float dmu = logRn - nb_mu[a];
                acc += nb_pref[a] * __expf(-dmu * dmu * nb_i2s2[a]);
            }
        }
        orow[tid] = acc * (1.0f / Rn);
    }

    // ---- Phase B1: count triplets per pair bucket ----
    for (int t = tid; t < ntrip; t += 256) {
        int rem = t, a = 0, rl = m - 1;
        while (rem >= rl) { rem -= rl; --rl; ++a; }
        const int c = a + 1 + rem;
        const int zj = nb_z[a], zk = nb_z[c];
        const int pmn = min(zj, zk), pmx = max(zj, zk);
        const int p = (pmn * (2 * NSPEC - pmn - 1)) / 2 + pmx;
        atomicAdd(&bcnt[p], 1);
    }
    __syncthreads();
    if (tid == 0) {
        int s = 0;
        for (int p = 0; p < NPAIRS; ++p) { bstart[p] = s; bcur[p] = s; s += bcnt[p]; }
    }
    __syncthreads();

    // ---- Phase B2: compute triplet terms, scatter into buckets ----
    for (int t = tid; t < ntrip; t += 256) {
        int rem = t, a = 0, rl = m - 1;
        while (rem >= rl) { rem -= rl; --rl; ++a; }
        const int c = a + 1 + rem;

        const float rij = nb_r[a], rik = nb_r[c];
        const float djx = nb_dx[a], djy = nb_dy[a], djz = nb_dz[a];
        const float dkx = nb_dx[c], dky = nb_dy[c], dkz = nb_dz[c];

        float cosi = (djx * dkx + djy * dky + djz * dkz) / (rij * rik);
        cosi = fminf(1.0f, fmaxf(-1.0f, cosi));

        // REFERENCE SEMANTICS: r_jk clamps to 1.0 when (j,k) pair is not
        // itself within cutoff (rs = where(within, r, 1.0)).
        const float ex = dkx - djx, ey = dky - djy, ez = dkz - djz;
        const float rjk = sqrtf(ex * ex + ey * ey + ez * ez);
        const float rjke = (rjk < RCUT_F) ? rjk : 1.0f;

        const float cosj = (rij * rij + rjke * rjke - rik * rik) / (2.0f * rij * rjke);
        const float cosk = (rik * rik + rjke * rjke - rij * rij) / (2.0f * rik * rjke);

        const float ksi = W3_F * (1.0f + 3.0f * cosi * cosj * cosk)
                        * __expf(-0.57f * __logf(rij * rik * rjke));
        const float w  = ksi * nb_fc[a] * nb_fc[c];
        const float wc = w * cosi;
        const float s1 = fmaxf(1.0f - cosi * cosi, 0.0f);
        const float ws = w * sqrtf(s1);
        const float d  = 0.5f * (rij + rik);

        const int zj = nb_z[a], zk = nb_z[c];
        const int pmn = min(zj, zk), pmx = max(zj, zk);
        const int p = (pmn * (2 * NSPEC - pmn - 1)) / 2 + pmx;

        const int slot = atomicAdd(&bcur[p], 1);
        trip_wc[slot] = wc; trip_ws[slot] = ws; trip_d[slot] = d;
    }
    __syncthreads();

    // ---- Phase C: thread (p, l) reduces its own bucket — no atomics ----
    if (tid < NPAIRS * NRS3) {     // 200 threads
        const int p = tid / NRS3;
        const int l = tid % NRS3;
        const float Rl = 0.3f * (float)(l + 1);   // RS3[l]
        const int s0 = bstart[p];
        const int s1 = s0 + bcnt[p];
        float ac = 0.0f, as_ = 0.0f;
        for (int s = s0; s < s1; ++s) {
            const float dd = trip_d[s] - Rl;       // broadcast reads (20 thr/addr)
            const float rad = __expf(-ETA3_F * dd * dd);
            ac  += trip_wc[s] * rad;
            as_ += trip_ws[s] * rad;
        }
        orow[REP2 + p * (NRS3 * 2) + l * 2 + 0] = ac;
        orow[REP2 + p * (NRS3 * 2) + l * 2 + 1] = as_;
    }
}

extern "C" void kernel_launch(void* const* d_in, const int* in_sizes, int n_in,
                              void* d_out, int out_size, void* d_ws, size_t ws_size,
                              hipStream_t stream) {
    const float* X           = (const float*)d_in[0];
    const int*   Z           = (const int*)d_in[1];
    // d_in[2] = atomIDs, d_in[3] = molIDs (unused by reference math)
    const int*   atom_counts = (const int*)d_in[4];
    float* out = (float*)d_out;

    fchl_kernel<<<B_MOL * A_MAX, 256, 0, stream>>>(X, Z, atom_counts, out);
}